// Round 4
// baseline (280.837 us; speedup 1.0000x reference)
//
#include <hip/hip_runtime.h>
#include <math.h>

#define NIMG 8
#define NCLS 19
#define IMG_H 512
#define IMG_W 512
#define HW (IMG_H * IMG_W)
#define NQ (HW / 4)          // 65536 quads per image
#define GRIDX 128            // blocks per image; 128*512 quads = NQ exactly
#define PQ 2                 // quads per thread (8 pixels)
#define BSTRIDE 21           // lane-bin row stride: gcd(21,32)=1 -> 2-way = free
#define TRASH 19             // bin for invalid / gated-off pixels
#define GBINS(acc, n, c) (((acc) * NIMG + (n)) * NCLS + (c))

__device__ inline float wave_reduce_add(float v) {
    #pragma unroll
    for (int off = 32; off > 0; off >>= 1)
        v += __shfl_down(v, off, 64);
    return v;
}

// ---------------------------------------------------------------------------
// Single-trip fused pass, class-outer loop with register-resident pixels.
// Per thread: 2 quads (8 px). Loop c=0..18 loads 2 float4/iter (prefetched),
// accumulating sum-exp and target-logit select. Branch-free LDS binning with
// trash bin; BCE done up-front to free edge/mask registers.
// ---------------------------------------------------------------------------
__global__ __launch_bounds__(256, 4) void main_kernel(
    const float* __restrict__ segin,
    const float* __restrict__ edgein,
    const int* __restrict__ segmask,
    const int* __restrict__ edgemask,
    float* __restrict__ g_bins,      // [4][NIMG][NCLS]
    float* __restrict__ g_sc)        // [NIMG][4]
{
    __shared__ float s_bins[4 * 64 * BSTRIDE];   // [acc][lane][class(21)]
    __shared__ float s_red[4][4];

    const int n = blockIdx.y;
    const int bx = blockIdx.x;
    const int tid = threadIdx.x;
    const int lane = tid & 63;
    const int wave = tid >> 6;

    for (int i = tid; i < 4 * 64 * BSTRIDE; i += 256) s_bins[i] = 0.f;

    const int q0 = bx * (256 * PQ) + tid;        // quad 0; quad 1 = q0 + 256

    const float4* segq  = (const float4*)(segin  + (size_t)n * NCLS * HW);
    const float4* edgeq = (const float4*)(edgein + (size_t)n * HW);
    const int4*   smq   = (const int4*)(segmask  + (size_t)n * HW);
    const int4*   emq   = (const int4*)(edgemask + (size_t)n * HW);

    // issue first class loads immediately (latency overlap with BCE below)
    float4 nxt0 = segq[q0];
    float4 nxt1 = segq[q0 + 256];

    const int4 t4a  = smq[q0];
    const int4 t4b  = smq[q0 + 256];
    const int4 te4a = emq[q0];
    const int4 te4b = emq[q0 + 256];
    const float4 e4a = edgeq[q0];
    const float4 e4b = edgeq[q0 + 256];

    __syncthreads();   // bins zeroed

    // ---- BCE + attention gates (frees e/te registers before class loop) ----
    float bp = 0.f, bn = 0.f, pc = 0.f, nc = 0.f;
    unsigned gate = 0u;
#define BCE1(E, TE, GBIT) do { \
        const float b_ = fmaxf((E), 0.f) - (E) * (float)(TE) \
                         + __logf(1.f + __expf(-fabsf(E))); \
        if ((TE) == 1)      { bp += b_; pc += 1.f; } \
        else if ((TE) == 0) { bn += b_; nc += 1.f; } \
        gate |= ((E) > 0.8f ? 1u : 0u) << (GBIT); \
    } while (0)
    BCE1(e4a.x, te4a.x, 0); BCE1(e4a.y, te4a.y, 1);
    BCE1(e4a.z, te4a.z, 2); BCE1(e4a.w, te4a.w, 3);
    BCE1(e4b.x, te4b.x, 4); BCE1(e4b.y, te4b.y, 5);
    BCE1(e4b.z, te4b.z, 6); BCE1(e4b.w, te4b.w, 7);
#undef BCE1

    // ---- clipped target classes (invalid -> TRASH) ----
    int tc[8];
    tc[0] = ((unsigned)t4a.x < NCLS) ? t4a.x : TRASH;
    tc[1] = ((unsigned)t4a.y < NCLS) ? t4a.y : TRASH;
    tc[2] = ((unsigned)t4a.z < NCLS) ? t4a.z : TRASH;
    tc[3] = ((unsigned)t4a.w < NCLS) ? t4a.w : TRASH;
    tc[4] = ((unsigned)t4b.x < NCLS) ? t4b.x : TRASH;
    tc[5] = ((unsigned)t4b.y < NCLS) ? t4b.y : TRASH;
    tc[6] = ((unsigned)t4b.z < NCLS) ? t4b.z : TRASH;
    tc[7] = ((unsigned)t4b.w < NCLS) ? t4b.w : TRASH;

    // ---- class-outer sum-exp with manual prefetch ----
    float se[8], xt[8];
    #pragma unroll
    for (int k = 0; k < 8; k++) { se[k] = 0.f; xt[k] = 0.f; }

    for (int c = 0; c < NCLS; c++) {
        const float4 cur0 = nxt0;
        const float4 cur1 = nxt1;
        if (c + 1 < NCLS) {
            nxt0 = segq[(size_t)(c + 1) * NQ + q0];
            nxt1 = segq[(size_t)(c + 1) * NQ + q0 + 256];
        }
        se[0] += __expf(cur0.x); xt[0] = (c == tc[0]) ? cur0.x : xt[0];
        se[1] += __expf(cur0.y); xt[1] = (c == tc[1]) ? cur0.y : xt[1];
        se[2] += __expf(cur0.z); xt[2] = (c == tc[2]) ? cur0.z : xt[2];
        se[3] += __expf(cur0.w); xt[3] = (c == tc[3]) ? cur0.w : xt[3];
        se[4] += __expf(cur1.x); xt[4] = (c == tc[4]) ? cur1.x : xt[4];
        se[5] += __expf(cur1.y); xt[5] = (c == tc[5]) ? cur1.y : xt[5];
        se[6] += __expf(cur1.z); xt[6] = (c == tc[6]) ? cur1.z : xt[6];
        se[7] += __expf(cur1.w); xt[7] = (c == tc[7]) ? cur1.w : xt[7];
    }

    // ---- branch-free LDS binning (trash bin absorbs invalid/ungated) ----
    float* b_slpt = &s_bins[(0 * 64 + lane) * BSTRIDE];
    float* b_scnt = &s_bins[(1 * 64 + lane) * BSTRIDE];
    float* b_alpt = &s_bins[(2 * 64 + lane) * BSTRIDE];
    float* b_acnt = &s_bins[(3 * 64 + lane) * BSTRIDE];
    #pragma unroll
    for (int k = 0; k < 8; k++) {
        const int t = tc[k];
        const float lp = xt[k] - __logf(se[k]);
        atomicAdd(&b_slpt[t], lp);
        atomicAdd(&b_scnt[t], 1.f);
        const int ta = ((gate >> k) & 1u) ? t : TRASH;
        atomicAdd(&b_alpt[ta], lp);
        atomicAdd(&b_acnt[ta], 1.f);
    }

    // ---- BCE block reduction ----
    bp = wave_reduce_add(bp);
    bn = wave_reduce_add(bn);
    pc = wave_reduce_add(pc);
    nc = wave_reduce_add(nc);
    if (lane == 0) { s_red[0][wave] = bp; s_red[1][wave] = bn;
                     s_red[2][wave] = pc; s_red[3][wave] = nc; }
    __syncthreads();

    if (tid < 4 * NCLS) {
        const int acc = tid / NCLS;
        const int c = tid - acc * NCLS;
        float s = 0.f;
        #pragma unroll 8
        for (int l = 0; l < 64; l++)
            s += s_bins[(acc * 64 + l) * BSTRIDE + c];
        atomicAdd(&g_bins[GBINS(acc, n, c)], s);
    } else if (tid < 4 * NCLS + 4) {
        const int k = tid - 4 * NCLS;
        atomicAdd(&g_sc[n * 4 + k],
                  s_red[k][0] + s_red[k][1] + s_red[k][2] + s_red[k][3]);
    }
}

// ---------------------------------------------------------------------------
// Finalize: weights from counts, weighted combines, 4 outputs. Reads 2.5 KB.
// ---------------------------------------------------------------------------
__global__ void final_kernel(const float* __restrict__ g_bins,
                             const float* __restrict__ g_sc,
                             float* __restrict__ out)
{
    __shared__ float s_seg[NIMG];
    __shared__ float s_att[NIMG];
    const int t = threadIdx.x;
    if (t < NIMG) {
        const int n = t;
        float tot = 0.f, tota = 0.f;
        for (int c = 0; c < NCLS; c++) {
            tot  += g_bins[GBINS(1, n, c)];
            tota += g_bins[GBINS(3, n, c)];
        }
        tot  = fmaxf(tot, 1.0f);
        tota = fmaxf(tota, 1.0f);
        float wp = 0.f, wplp = 0.f, wpa = 0.f, wplpa = 0.f;
        for (int c = 0; c < NCLS; c++) {
            const float cs = g_bins[GBINS(1, n, c)];
            const float ca = g_bins[GBINS(3, n, c)];
            const float w  = (cs > 0.f) ? (2.0f - cs / tot ) : 1.0f;
            const float wa = (ca > 0.f) ? (2.0f - ca / tota) : 1.0f;
            wp    += w * cs;    wplp  += w * g_bins[GBINS(0, n, c)];
            wpa   += wa * ca;   wplpa += wa * g_bins[GBINS(2, n, c)];
        }
        s_seg[n] = -wplp  / fmaxf(wp,  1e-12f);
        s_att[n] = -wplpa / fmaxf(wpa, 1e-12f);
    }
    __syncthreads();
    if (t == 0) {
        float seg = 0.f, att = 0.f, bpt = 0.f, bnt = 0.f, pct = 0.f, nct = 0.f;
        for (int n = 0; n < NIMG; n++) {
            seg += s_seg[n];
            att += s_att[n];
            bpt += g_sc[n * 4 + 0];
            bnt += g_sc[n * 4 + 1];
            pct += g_sc[n * 4 + 2];
            nct += g_sc[n * 4 + 3];
        }
        const float s = fmaxf(pct + nct, 1.0f);
        const float bce = (nct / s) * bpt + (pct / s) * bnt;
        out[0] = seg;
        out[1] = 20.0f * bce / (float)(NIMG * HW);
        out[2] = att;
        out[3] = 0.0f;
    }
}

extern "C" void kernel_launch(void* const* d_in, const int* in_sizes, int n_in,
                              void* d_out, int out_size, void* d_ws, size_t ws_size,
                              hipStream_t stream) {
    const float* segin    = (const float*)d_in[0];
    const float* edgein   = (const float*)d_in[1];
    const int*   segmask  = (const int*)d_in[2];
    const int*   edgemask = (const int*)d_in[3];
    float* out = (float*)d_out;

    float* g_bins = (float*)d_ws;                 // 4*8*19 = 608 floats
    float* g_sc   = g_bins + 4 * NIMG * NCLS;     // 8*4 = 32 floats

    hipMemsetAsync(d_ws, 0, (4 * NIMG * NCLS + 4 * NIMG) * sizeof(float), stream);

    main_kernel<<<dim3(GRIDX, NIMG), 256, 0, stream>>>(
        segin, edgein, segmask, edgemask, g_bins, g_sc);
    final_kernel<<<1, 64, 0, stream>>>(g_bins, g_sc, out);
}

// Round 5
// 256.933 us; speedup vs baseline: 1.0930x; 1.0930x over previous
//
#include <hip/hip_runtime.h>
#include <math.h>

#define NIMG 8
#define NCLS 19
#define IMG_H 512
#define IMG_W 512
#define HW (IMG_H * IMG_W)
#define NQ (HW / 4)          // 65536 quads per image
#define GRIDX 64             // blocks per image
#define QSTRIDE (GRIDX * 256)  // 16384 quads per iteration
#define NITER (NQ / QSTRIDE)   // 4 iterations per thread
#define BSTRIDE 21           // lane-bin row stride: gcd(21,32)=1 -> 2-way = free
#define TRASH 19             // bin for invalid / gated-off pixels
#define GBINS(acc, n, c) (((acc) * NIMG + (n)) * NCLS + (c))

__device__ inline float wave_reduce_add(float v) {
    #pragma unroll
    for (int off = 32; off > 0; off >>= 1)
        v += __shfl_down(v, off, 64);
    return v;
}

// ---------------------------------------------------------------------------
// Fused pass. Per thread-iteration: issue ALL 22 loads (3 mask/edge + 19
// segin float4), then a sched_barrier(0) pins the batch (compiler cannot sink
// loads into the compute), then BCE/gates (masks arrive first) and the
// 19-class sum-exp consume the batch. 8 waves/CU x 22KB in flight -> HBM-bound.
// ---------------------------------------------------------------------------
__global__ __launch_bounds__(256, 2) void main_kernel(
    const float* __restrict__ segin,
    const float* __restrict__ edgein,
    const int* __restrict__ segmask,
    const int* __restrict__ edgemask,
    float* __restrict__ g_bins,      // [4][NIMG][NCLS]
    float* __restrict__ g_sc)        // [NIMG][4]
{
    __shared__ float s_bins[4 * 64 * BSTRIDE];   // [acc][lane][class(21)]
    __shared__ float s_red[4][4];

    const int n = blockIdx.y;
    const int bx = blockIdx.x;
    const int tid = threadIdx.x;
    const int lane = tid & 63;
    const int wave = tid >> 6;

    for (int i = tid; i < 4 * 64 * BSTRIDE; i += 256) s_bins[i] = 0.f;
    __syncthreads();

    float* b_slpt = &s_bins[(0 * 64 + lane) * BSTRIDE];
    float* b_scnt = &s_bins[(1 * 64 + lane) * BSTRIDE];
    float* b_alpt = &s_bins[(2 * 64 + lane) * BSTRIDE];
    float* b_acnt = &s_bins[(3 * 64 + lane) * BSTRIDE];

    const float4* segq  = (const float4*)(segin  + (size_t)n * NCLS * HW);
    const float4* edgeq = (const float4*)(edgein + (size_t)n * HW);
    const int4*   smq   = (const int4*)(segmask  + (size_t)n * HW);
    const int4*   emq   = (const int4*)(edgemask + (size_t)n * HW);

    float bp = 0.f, bn = 0.f, pc = 0.f, nc = 0.f;

    int q = bx * 256 + tid;
    #pragma unroll 1
    for (int it = 0; it < NITER; ++it, q += QSTRIDE) {
        // ---- issue every load of this iteration, then pin the boundary ----
        const int4 t4  = smq[q];
        const int4 te4 = emq[q];
        const float4 e4 = edgeq[q];
        float4 xs[NCLS];
        #pragma unroll
        for (int c = 0; c < NCLS; c++)
            xs[c] = segq[(size_t)c * NQ + q];
        __builtin_amdgcn_sched_barrier(0);

        // ---- BCE + attention gates (needs only masks: overlaps segin tail) --
        unsigned gate = 0u;
#define BCE1(E, TE, GBIT) do { \
            const float b_ = fmaxf((E), 0.f) - (E) * (float)(TE) \
                             + __logf(1.f + __expf(-fabsf(E))); \
            if ((TE) == 1)      { bp += b_; pc += 1.f; } \
            else if ((TE) == 0) { bn += b_; nc += 1.f; } \
            gate |= ((E) > 0.8f ? 1u : 0u) << (GBIT); \
        } while (0)
        BCE1(e4.x, te4.x, 0); BCE1(e4.y, te4.y, 1);
        BCE1(e4.z, te4.z, 2); BCE1(e4.w, te4.w, 3);
#undef BCE1

        const int tc0 = ((unsigned)t4.x < NCLS) ? t4.x : TRASH;
        const int tc1 = ((unsigned)t4.y < NCLS) ? t4.y : TRASH;
        const int tc2 = ((unsigned)t4.z < NCLS) ? t4.z : TRASH;
        const int tc3 = ((unsigned)t4.w < NCLS) ? t4.w : TRASH;

        float se0 = 0.f, se1 = 0.f, se2 = 0.f, se3 = 0.f;
        float xt0 = 0.f, xt1 = 0.f, xt2 = 0.f, xt3 = 0.f;
        #pragma unroll
        for (int c = 0; c < NCLS; c++) {
            se0 += __expf(xs[c].x); xt0 = (c == tc0) ? xs[c].x : xt0;
            se1 += __expf(xs[c].y); xt1 = (c == tc1) ? xs[c].y : xt1;
            se2 += __expf(xs[c].z); xt2 = (c == tc2) ? xs[c].z : xt2;
            se3 += __expf(xs[c].w); xt3 = (c == tc3) ? xs[c].w : xt3;
        }
        const float lp0 = xt0 - __logf(se0);
        const float lp1 = xt1 - __logf(se1);
        const float lp2 = xt2 - __logf(se2);
        const float lp3 = xt3 - __logf(se3);

        // ---- branch-free LDS binning (trash bin absorbs invalid/ungated) ----
#define BIN1(TC, LP, GBIT) do { \
            atomicAdd(&b_slpt[(TC)], (LP)); \
            atomicAdd(&b_scnt[(TC)], 1.f); \
            const int ta_ = ((gate >> (GBIT)) & 1u) ? (TC) : TRASH; \
            atomicAdd(&b_alpt[ta_], (LP)); \
            atomicAdd(&b_acnt[ta_], 1.f); \
        } while (0)
        BIN1(tc0, lp0, 0); BIN1(tc1, lp1, 1);
        BIN1(tc2, lp2, 2); BIN1(tc3, lp3, 3);
#undef BIN1
    }

    // ---- BCE block reduction ----
    bp = wave_reduce_add(bp);
    bn = wave_reduce_add(bn);
    pc = wave_reduce_add(pc);
    nc = wave_reduce_add(nc);
    if (lane == 0) { s_red[0][wave] = bp; s_red[1][wave] = bn;
                     s_red[2][wave] = pc; s_red[3][wave] = nc; }
    __syncthreads();

    if (tid < 4 * NCLS) {
        const int acc = tid / NCLS;
        const int c = tid - acc * NCLS;
        float s = 0.f;
        #pragma unroll 8
        for (int l = 0; l < 64; l++)
            s += s_bins[(acc * 64 + l) * BSTRIDE + c];
        atomicAdd(&g_bins[GBINS(acc, n, c)], s);
    } else if (tid < 4 * NCLS + 4) {
        const int k = tid - 4 * NCLS;
        atomicAdd(&g_sc[n * 4 + k],
                  s_red[k][0] + s_red[k][1] + s_red[k][2] + s_red[k][3]);
    }
}

// ---------------------------------------------------------------------------
// Finalize: weights from counts, weighted combines, 4 outputs. Reads 2.5 KB.
// ---------------------------------------------------------------------------
__global__ void final_kernel(const float* __restrict__ g_bins,
                             const float* __restrict__ g_sc,
                             float* __restrict__ out)
{
    __shared__ float s_seg[NIMG];
    __shared__ float s_att[NIMG];
    const int t = threadIdx.x;
    if (t < NIMG) {
        const int n = t;
        float tot = 0.f, tota = 0.f;
        for (int c = 0; c < NCLS; c++) {
            tot  += g_bins[GBINS(1, n, c)];
            tota += g_bins[GBINS(3, n, c)];
        }
        tot  = fmaxf(tot, 1.0f);
        tota = fmaxf(tota, 1.0f);
        float wp = 0.f, wplp = 0.f, wpa = 0.f, wplpa = 0.f;
        for (int c = 0; c < NCLS; c++) {
            const float cs = g_bins[GBINS(1, n, c)];
            const float ca = g_bins[GBINS(3, n, c)];
            const float w  = (cs > 0.f) ? (2.0f - cs / tot ) : 1.0f;
            const float wa = (ca > 0.f) ? (2.0f - ca / tota) : 1.0f;
            wp    += w * cs;    wplp  += w * g_bins[GBINS(0, n, c)];
            wpa   += wa * ca;   wplpa += wa * g_bins[GBINS(2, n, c)];
        }
        s_seg[n] = -wplp  / fmaxf(wp,  1e-12f);
        s_att[n] = -wplpa / fmaxf(wpa, 1e-12f);
    }
    __syncthreads();
    if (t == 0) {
        float seg = 0.f, att = 0.f, bpt = 0.f, bnt = 0.f, pct = 0.f, nct = 0.f;
        for (int n = 0; n < NIMG; n++) {
            seg += s_seg[n];
            att += s_att[n];
            bpt += g_sc[n * 4 + 0];
            bnt += g_sc[n * 4 + 1];
            pct += g_sc[n * 4 + 2];
            nct += g_sc[n * 4 + 3];
        }
        const float s = fmaxf(pct + nct, 1.0f);
        const float bce = (nct / s) * bpt + (pct / s) * bnt;
        out[0] = seg;
        out[1] = 20.0f * bce / (float)(NIMG * HW);
        out[2] = att;
        out[3] = 0.0f;
    }
}

extern "C" void kernel_launch(void* const* d_in, const int* in_sizes, int n_in,
                              void* d_out, int out_size, void* d_ws, size_t ws_size,
                              hipStream_t stream) {
    const float* segin    = (const float*)d_in[0];
    const float* edgein   = (const float*)d_in[1];
    const int*   segmask  = (const int*)d_in[2];
    const int*   edgemask = (const int*)d_in[3];
    float* out = (float*)d_out;

    float* g_bins = (float*)d_ws;                 // 4*8*19 = 608 floats
    float* g_sc   = g_bins + 4 * NIMG * NCLS;     // 8*4 = 32 floats

    hipMemsetAsync(d_ws, 0, (4 * NIMG * NCLS + 4 * NIMG) * sizeof(float), stream);

    main_kernel<<<dim3(GRIDX, NIMG), 256, 0, stream>>>(
        segin, edgein, segmask, edgemask, g_bins, g_sc);
    final_kernel<<<1, 64, 0, stream>>>(g_bins, g_sc, out);
}